// Round 10
// baseline (1085.703 us; speedup 1.0000x reference)
//
#include <hip/hip_runtime.h>
#include <math.h>

#define DEV __device__ __forceinline__

typedef __attribute__((ext_vector_type(4))) float f32x4;
typedef __attribute__((ext_vector_type(8))) short bf16x8;

DEV ushort f2bf(float x) {
  unsigned u = __float_as_uint(x);
  u = (u + 0x7FFFu + ((u >> 16) & 1u)) >> 16;
  return (ushort)u;
}

DEV float bf2f(ushort u) { return __uint_as_float(((unsigned)u) << 16); }

DEV ushort4 cvt4(float4 f) {
  ushort4 u;
  u.x = f2bf(f.x); u.y = f2bf(f.y); u.z = f2bf(f.z); u.w = f2bf(f.w);
  return u;
}

DEV float gelu_exact(float x) {
  return 0.5f * x * (1.0f + erff(x * 0.70710678118654752f));
}

DEV void async16(const void* g, void* l) {
  __builtin_amdgcn_global_load_lds((const __attribute__((address_space(1))) void*)g,
                                   (__attribute__((address_space(3))) void*)l, 16, 0, 0);
}

// ---------------------------------------------------------------------------
// One-shot preamble: f32->bf16 weight conversions + qkv/kv packing + masks=0.
// ---------------------------------------------------------------------------
__global__ void prep_all(const float* __restrict__ features, const float* __restrict__ tok_w,
                         const float* __restrict__ sa_qw, const float* __restrict__ sa_kw,
                         const float* __restrict__ sa_vw, const float* __restrict__ sa_ow,
                         const float* __restrict__ ca_qw, const float* __restrict__ ca_kw,
                         const float* __restrict__ ca_vw, const float* __restrict__ ca_ow,
                         const float* __restrict__ ffn_w1, const float* __restrict__ ffn_w2,
                         const float* __restrict__ sa_qb, const float* __restrict__ sa_kb,
                         const float* __restrict__ sa_vb, const float* __restrict__ ca_kb,
                         const float* __restrict__ ca_vb,
                         ushort* __restrict__ featbf, ushort* __restrict__ tokwbf,
                         ushort* __restrict__ saowbf, ushort* __restrict__ caqwbf,
                         ushort* __restrict__ caowbf, ushort* __restrict__ w1bf,
                         ushort* __restrict__ w2bf, ushort* __restrict__ qkvwbf,
                         ushort* __restrict__ kvwbf, float* __restrict__ qkvb,
                         float* __restrict__ kvb, float* __restrict__ masks) {
  long i = (long)blockIdx.x * 256 + threadIdx.x;
  if (i < 1572864) { ((ushort4*)featbf)[i] = cvt4(((const float4*)features)[i]); return; }
  i -= 1572864;
  if (i < 98304) { ((ushort4*)tokwbf)[i] = cvt4(((const float4*)tok_w)[i]); return; }
  i -= 98304;
  if (i < 262144) { ((ushort4*)saowbf)[i] = cvt4(((const float4*)sa_ow)[i]); return; }
  i -= 262144;
  if (i < 262144) { ((ushort4*)caqwbf)[i] = cvt4(((const float4*)ca_qw)[i]); return; }
  i -= 262144;
  if (i < 262144) { ((ushort4*)caowbf)[i] = cvt4(((const float4*)ca_ow)[i]); return; }
  i -= 262144;
  if (i < 1048576) { ((ushort4*)w1bf)[i] = cvt4(((const float4*)ffn_w1)[i]); return; }
  i -= 1048576;
  if (i < 1048576) { ((ushort4*)w2bf)[i] = cvt4(((const float4*)ffn_w2)[i]); return; }
  i -= 1048576;
  if (i < 786432) {  // qkv weight pack: [L][3*512][512]
    const long o = i * 4;
    const int layer = (int)(o / 786432), r = (int)(o % 786432);
    const int sel = r / 262144, off = r % 262144;
    const float* s = (sel == 0 ? sa_qw : sel == 1 ? sa_kw : sa_vw) + (size_t)layer * 262144 + off;
    ((ushort4*)qkvwbf)[i] = cvt4(*(const float4*)s);
    return;
  }
  i -= 786432;
  if (i < 524288) {  // kv weight pack: [L][2*512][512]
    const long o = i * 4;
    const int layer = (int)(o / 524288), r = (int)(o % 524288);
    const int sel = r / 262144, off = r % 262144;
    const float* s = (sel == 0 ? ca_kw : ca_vw) + (size_t)layer * 262144 + off;
    ((ushort4*)kvwbf)[i] = cvt4(*(const float4*)s);
    return;
  }
  i -= 524288;
  if (i < 1536) {
    const long o = i * 4;
    const int layer = (int)(o / 1536), r = (int)(o % 1536);
    const int sel = r / 512, off = r % 512;
    const float* s = (sel == 0 ? sa_qb : sel == 1 ? sa_kb : sa_vb) + layer * 512 + off;
    ((float4*)qkvb)[i] = *(const float4*)s;
    return;
  }
  i -= 1536;
  if (i < 1024) {
    const long o = i * 4;
    const int layer = (int)(o / 1024), r = (int)(o % 1024);
    const int sel = r / 512, off = r % 512;
    const float* s = (sel == 0 ? ca_kb : ca_vb) + layer * 512 + off;
    ((float4*)kvb)[i] = *(const float4*)s;
    return;
  }
  i -= 1024;
  if (i < 22528) {  // masks zero-init (8*1024*11 floats = 22528 float4)
    ((float4*)masks)[i] = make_float4(0.f, 0.f, 0.f, 0.f);
  }
}

// ---------------------------------------------------------------------------
// 128x128-tile bf16 GEMM:  Y[M,N] = A[M,K] @ W[N,K]^T + bias
// XCD-locality: m-tile = blockIdx.x (fastest varying).
// LDS XOR chunk-swizzle: LDS chunk q of row r holds global 16B-chunk q^(r&3)
// (staging lane loads chunk (lane&3)^(srow&3); frag reads chunk q^(ln&3)).
// Cuts the 8-way bank conflict of 64B-stride rows to 4-way; no padding needed
// so global_load_lds contiguity (m104) is preserved.
// EPI 2: Ybf=bf16(gelu)  5: l2norm cols<512, plain rest (kv-slots)
// EPI 6: l2norm cols<1024, q-chunk (cols<512) additionally x0.125 (qkv)
// ---------------------------------------------------------------------------
template <int EPI>
__launch_bounds__(256, 2)
__global__ void gemm_bt(const ushort* __restrict__ A, const ushort* __restrict__ W,
                        const float* __restrict__ bias, float* __restrict__ Yf,
                        ushort* __restrict__ Ybf, int M, int N, int K) {
  __shared__ ushort As[128 * 32];
  __shared__ ushort Bs[128 * 32];
  const int tid  = threadIdx.x;
  const int lane = tid & 63;
  const int wave = tid >> 6;
  const int wr = wave >> 1, wc = wave & 1;
  const int m0 = blockIdx.x * 128, n0 = blockIdx.y * 128;   // m fastest-varying
  const int q = lane >> 4, ln = lane & 15;
  const int srow = lane >> 2;
  const int scol = (((lane & 3) ^ (srow & 3)) & 3) * 8;     // XOR-swizzled source chunk

  f32x4 acc[4][4] = {};

  const ushort* gA = A + (size_t)(m0 + wave * 32 + srow) * K + scol;
  const ushort* gB = W + (size_t)(n0 + wave * 32 + srow) * K + scol;
  ushort* lA = &As[(wave * 32) * 32];
  ushort* lB = &Bs[(wave * 32) * 32];
  const int rsw = (q ^ (ln & 3)) * 8;                        // read-side swizzled chunk

  for (int k0 = 0; k0 < K; k0 += 32) {
    async16(gA + k0, lA);
    async16(gA + k0 + (size_t)16 * K, lA + 16 * 32);   // rows +16: (r+16)&3 == r&3
    async16(gB + k0, lB);
    async16(gB + k0 + (size_t)16 * K, lB + 16 * 32);
    __syncthreads();
    bf16x8 af[4], bfr[4];
#pragma unroll
    for (int t = 0; t < 4; ++t)
      af[t] = *(const bf16x8*)&As[(wr * 64 + t * 16 + ln) * 32 + rsw];
#pragma unroll
    for (int t = 0; t < 4; ++t)
      bfr[t] = *(const bf16x8*)&Bs[(wc * 64 + t * 16 + ln) * 32 + rsw];
#pragma unroll
    for (int mt = 0; mt < 4; ++mt)
#pragma unroll
      for (int nt = 0; nt < 4; ++nt)
        acc[mt][nt] = __builtin_amdgcn_mfma_f32_16x16x32_bf16(af[mt], bfr[nt], acc[mt][nt], 0, 0, 0);
    __syncthreads();
  }

  if (EPI >= 4) {
    const int chunk = (n0 + wc * 64) >> 9;
    const bool donorm = (EPI == 5 && chunk == 0) || (EPI == 6 && chunk < 2);
    const bool doscale = (EPI == 6 && chunk == 0);
#pragma unroll
    for (int mt = 0; mt < 4; ++mt) {
      const int gm = m0 + wr * 64 + mt * 16 + q * 4;
      float val[4][4];  // [nt][r]
#pragma unroll
      for (int nt = 0; nt < 4; ++nt) {
        const float bi = bias[n0 + wc * 64 + nt * 16 + ln];
#pragma unroll
        for (int r = 0; r < 4; ++r) val[nt][r] = acc[mt][nt][r] + bi;
      }
#pragma unroll
      for (int r = 0; r < 4; ++r) {
        float mult = 1.f;
        if (donorm) {
          float ss = val[0][r]*val[0][r] + val[1][r]*val[1][r] +
                     val[2][r]*val[2][r] + val[3][r]*val[3][r];
          ss += __shfl_xor(ss, 1);
          ss += __shfl_xor(ss, 2);
          ss += __shfl_xor(ss, 4);
          ss += __shfl_xor(ss, 8);
          mult = 1.f / fmaxf(sqrtf(ss), 1e-6f);
          if (doscale) mult *= 0.125f;
        }
#pragma unroll
        for (int nt = 0; nt < 4; ++nt) {
          const int gn = n0 + wc * 64 + nt * 16 + ln;
          Ybf[(size_t)(gm + r) * N + gn] = f2bf(val[nt][r] * mult);
        }
      }
    }
  } else {
#pragma unroll
    for (int mt = 0; mt < 4; ++mt) {
      const int gm = m0 + wr * 64 + mt * 16 + q * 4;
#pragma unroll
      for (int nt = 0; nt < 4; ++nt) {
        const int gn = n0 + wc * 64 + nt * 16 + ln;
        const float bi = bias[gn];
#pragma unroll
        for (int r = 0; r < 4; ++r) {
          const float val = acc[mt][nt][r] + bi;
          const size_t idx = (size_t)(gm + r) * N + gn;
          if (EPI == 0)      Yf[idx] = val;
          else if (EPI == 1) Yf[idx] += val;
          else               Ybf[idx] = f2bf(gelu_exact(val));
        }
      }
    }
  }
}

// ---------------------------------------------------------------------------
// 64x64-tile bf16 GEMM (4 blocks/CU, R7-proven for N=512 shapes).
// Same XOR chunk-swizzle as gemm_bt. XCD-locality: m-tile = blockIdx.x.
// EPI 0: Yf=val  1: Yf+=val  4: per-head l2norm x0.125 bf16 (cross-wave LDS red)
// ---------------------------------------------------------------------------
template <int EPI>
__launch_bounds__(256, 4)
__global__ void gemm_bt64(const ushort* __restrict__ A, const ushort* __restrict__ W,
                          const float* __restrict__ bias, float* __restrict__ Yf,
                          ushort* __restrict__ Ybf, int M, int N, int K) {
  __shared__ ushort As[64 * 32];
  __shared__ ushort Bs[64 * 32];
  __shared__ float red[2][32][2];
  const int tid = threadIdx.x, lane = tid & 63, wave = tid >> 6;
  const int wr = wave >> 1, wc = wave & 1;
  const int m0 = blockIdx.x * 64, n0 = blockIdx.y * 64;   // m fastest-varying
  const int q = lane >> 4, ln = lane & 15;
  const int srow = lane >> 2;
  const int scol = (((lane & 3) ^ (srow & 3)) & 3) * 8;   // XOR-swizzled source chunk
  const int rsw = (q ^ (ln & 3)) * 8;

  f32x4 acc[2][2] = {};
  const ushort* gA = A + (size_t)(m0 + wave * 16 + srow) * K + scol;
  const ushort* gB = W + (size_t)(n0 + wave * 16 + srow) * K + scol;
  ushort* lA = &As[wave * 16 * 32];
  ushort* lB = &Bs[wave * 16 * 32];

  for (int k0 = 0; k0 < K; k0 += 32) {
    async16(gA + k0, lA);
    async16(gB + k0, lB);
    __syncthreads();
    bf16x8 af[2], bfr[2];
#pragma unroll
    for (int t = 0; t < 2; ++t)
      af[t] = *(const bf16x8*)&As[(wr * 32 + t * 16 + ln) * 32 + rsw];
#pragma unroll
    for (int t = 0; t < 2; ++t)
      bfr[t] = *(const bf16x8*)&Bs[(wc * 32 + t * 16 + ln) * 32 + rsw];
#pragma unroll
    for (int mt = 0; mt < 2; ++mt)
#pragma unroll
      for (int nt = 0; nt < 2; ++nt)
        acc[mt][nt] = __builtin_amdgcn_mfma_f32_16x16x32_bf16(af[mt], bfr[nt], acc[mt][nt], 0, 0, 0);
    __syncthreads();
  }

  if (EPI == 4) {
    float val[2][2][4];  // [mt][nt][r]
#pragma unroll
    for (int mt = 0; mt < 2; ++mt)
#pragma unroll
      for (int nt = 0; nt < 2; ++nt) {
        const float bi = bias[n0 + wc * 32 + nt * 16 + ln];
#pragma unroll
        for (int r = 0; r < 4; ++r) val[mt][nt][r] = acc[mt][nt][r] + bi;
      }
#pragma unroll
    for (int mt = 0; mt < 2; ++mt)
#pragma unroll
      for (int r = 0; r < 4; ++r) {
        float ss = val[mt][0][r]*val[mt][0][r] + val[mt][1][r]*val[mt][1][r];
        ss += __shfl_xor(ss, 1);
        ss += __shfl_xor(ss, 2);
        ss += __shfl_xor(ss, 4);
        ss += __shfl_xor(ss, 8);
        if (ln == 0) red[wr][mt * 16 + q * 4 + r][wc] = ss;
      }
    __syncthreads();
#pragma unroll
    for (int mt = 0; mt < 2; ++mt) {
      const int gm = m0 + wr * 32 + mt * 16 + q * 4;
#pragma unroll
      for (int r = 0; r < 4; ++r) {
        const float tot = red[wr][mt * 16 + q * 4 + r][0] + red[wr][mt * 16 + q * 4 + r][1];
        const float inv = 0.125f / fmaxf(sqrtf(tot), 1e-6f);
#pragma unroll
        for (int nt = 0; nt < 2; ++nt) {
          const int gn = n0 + wc * 32 + nt * 16 + ln;
          Ybf[(size_t)(gm + r) * N + gn] = f2bf(val[mt][nt][r] * inv);
        }
      }
    }
  } else {
#pragma unroll
    for (int mt = 0; mt < 2; ++mt) {
      const int gm = m0 + wr * 32 + mt * 16 + q * 4;
#pragma unroll
      for (int nt = 0; nt < 2; ++nt) {
        const int gn = n0 + wc * 32 + nt * 16 + ln;
        const float bi = bias[gn];
#pragma unroll
        for (int r = 0; r < 4; ++r) {
          const float val = acc[mt][nt][r] + bi;
          const size_t idx = (size_t)(gm + r) * N + gn;
          if (EPI == 0) Yf[idx] = val;
          else          Yf[idx] += val;
        }
      }
    }
  }
}

// ---------------------------------------------------------------------------
// LayerNorm over D=512, one wave per row. BF=1: bf16 out, BF=0: f32 out
// ---------------------------------------------------------------------------
template <int BF>
__launch_bounds__(256)
__global__ void ln512(const float* __restrict__ X, const float* __restrict__ G,
                      const float* __restrict__ Bb, void* __restrict__ Yv, int rows) {
  const int lane = threadIdx.x & 63;
  const int wave = threadIdx.x >> 6;
  const int row = blockIdx.x * 4 + wave;
  if (row >= rows) return;
  const float* x = X + (size_t)row * 512 + lane * 8;
  float4 v0 = *(const float4*)x;
  float4 v1 = *(const float4*)(x + 4);
  float s = v0.x + v0.y + v0.z + v0.w + v1.x + v1.y + v1.z + v1.w;
#pragma unroll
  for (int off = 32; off; off >>= 1) s += __shfl_xor(s, off);
  const float mean = s * (1.f / 512.f);
  float d[8] = {v0.x - mean, v0.y - mean, v0.z - mean, v0.w - mean,
                v1.x - mean, v1.y - mean, v1.z - mean, v1.w - mean};
  float ss = d[0]*d[0] + d[1]*d[1] + d[2]*d[2] + d[3]*d[3] +
             d[4]*d[4] + d[5]*d[5] + d[6]*d[6] + d[7]*d[7];
#pragma unroll
  for (int off = 32; off; off >>= 1) ss += __shfl_xor(ss, off);
  const float rstd = rsqrtf(ss * (1.f / 512.f) + 1e-5f);
  const float* gp = G + lane * 8;
  const float* bp = Bb + lane * 8;
  float4 g0 = *(const float4*)gp, g1 = *(const float4*)(gp + 4);
  float4 b0 = *(const float4*)bp, b1 = *(const float4*)(bp + 4);
  float y[8];
  y[0] = d[0]*rstd*g0.x + b0.x; y[1] = d[1]*rstd*g0.y + b0.y;
  y[2] = d[2]*rstd*g0.z + b0.z; y[3] = d[3]*rstd*g0.w + b0.w;
  y[4] = d[4]*rstd*g1.x + b1.x; y[5] = d[5]*rstd*g1.y + b1.y;
  y[6] = d[6]*rstd*g1.z + b1.z; y[7] = d[7]*rstd*g1.w + b1.w;
  if (BF) {
    ushort* o = (ushort*)Yv + (size_t)row * 512 + lane * 8;
    ushort4 u0, u1;
    u0.x = f2bf(y[0]); u0.y = f2bf(y[1]); u0.z = f2bf(y[2]); u0.w = f2bf(y[3]);
    u1.x = f2bf(y[4]); u1.y = f2bf(y[5]); u1.z = f2bf(y[6]); u1.w = f2bf(y[7]);
    *(ushort4*)o = u0; *(ushort4*)(o + 4) = u1;
  } else {
    float* o = (float*)Yv + (size_t)row * 512 + lane * 8;
    *(float4*)o = make_float4(y[0], y[1], y[2], y[3]);
    *(float4*)(o + 4) = make_float4(y[4], y[5], y[6], y[7]);
  }
}

// ---------------------------------------------------------------------------
// Causal self-attention, MFMA flash-style, 128-row Q tiles, pipelined staging.
// Q/K l2-normalized and Q x0.125 => |s| <= ~0.127 => NO online max needed.
// ---------------------------------------------------------------------------
__launch_bounds__(256, 2)
__global__ void attn_self_mfma(const ushort* __restrict__ QKV, ushort* __restrict__ O) {
  constexpr int LDK = 72;
  __shared__ ushort Ks[64 * LDK];
  __shared__ ushort Vt[64 * LDK];          // transposed: [d][k]
  __shared__ ushort Ps[4][32 * LDK];       // per-wave P scratch; doubles as Q staging
  ushort* Qstage = &Ps[0][0];              // [128][LDK]
  const int bi = blockIdx.x;
  const int half = bi >> 8, j = bi & 255;
  const int qt = half ? 7 - (j >> 5) : (j >> 5);
  const int bh = (half << 5) | (j & 31);
  const int b = bh >> 3, h = bh & 7;
  const size_t base = (size_t)b * 1024 * 1536 + h * 64;
  const int tid = threadIdx.x, lane = tid & 63, wave = tid >> 6;
  const int quad = lane >> 4, ln = lane & 15;

  const int kr = tid >> 2, kc0 = (tid & 3) * 16;
  const ushort* kbase = QKV + base + 512 + (size_t)kr * 1536 + kc0;
  const int vk = (tid & 31) * 2, vd0 = (tid >> 5) * 8;
  const ushort* vbase = QKV + base + 1024 + (size_t)vk * 1536 + vd0;

#pragma unroll
  for (int it = 0; it < 4; ++it) {
    const int idx = tid + 256 * it;
    const int r = idx >> 3, c = (idx & 7) * 8;
    *(uint4*)&Qstage[r * LDK + c] =
        *(const uint4*)(QKV + base + (size_t)(qt * 128 + r) * 1536 + c);
  }
  uint4 kreg0 = *(const uint4*)kbase;
  uint4 kreg1 = *(const uint4*)(kbase + 8);
  uint4 vreg0 = *(const uint4*)vbase;
  uint4 vreg1 = *(const uint4*)(vbase + 1536);
  __syncthreads();
  bf16x8 qf[2][2];
#pragma unroll
  for (int mt = 0; mt < 2; ++mt)
#pragma unroll
    for (int kc = 0; kc < 2; ++kc)
      qf[mt][kc] = *(const bf16x8*)&Qstage[(wave * 32 + mt * 16 + ln) * LDK + kc * 32 + quad * 8];

  float l_r[2][4] = {};
  f32x4 o_acc[2][4] = {};

  const int ktmax = 2 * qt + 1;
  for (int kt = 0; kt <= ktmax; ++kt) {
    __syncthreads();
    *(uint4*)&Ks[kr * LDK + kc0]     = kreg0;
    *(uint4*)&Ks[kr * LDK + kc0 + 8] = kreg1;
    {
      const ushort* ua = (const ushort*)&vreg0;
      const ushort* ub = (const ushort*)&vreg1;
#pragma unroll
      for (int jj = 0; jj < 8; ++jj)
        *(unsigned*)&Vt[(vd0 + jj) * LDK + vk] = (unsigned)ua[jj] | ((unsigned)ub[jj] << 16);
    }
    __syncthreads();
    if (kt < ktmax) {
      const size_t nb = (size_t)(kt + 1) * 64 * 1536;
      kreg0 = *(const uint4*)(kbase + nb);
      kreg1 = *(const uint4*)(kbase + nb + 8);
      vreg0 = *(const uint4*)(vbase + nb);
      vreg1 = *(const uint4*)(vbase + nb + 1536);
    }

    bf16x8 kf[4][2];
#pragma unroll
    for (int kb = 0; kb < 4; ++kb)
#pragma unroll
      for (int kc = 0; kc < 2; ++kc)
        kf[kb][kc] = *(const bf16x8*)&Ks[(kb * 16 + ln) * LDK + kc * 32 + quad * 8];
    f32x4 s[2][4] = {};
#pragma unroll
    for (int mt = 0; mt < 2; ++mt)
#pragma unroll
      for (int kb = 0; kb < 4; ++kb) {
        s[mt][kb] = __builtin_amdgcn_mfma_f32_16x16x32_bf16(qf[mt][0], kf[kb][0], s[mt][kb], 0, 0, 0);
        s[mt][kb] = __builtin_amdgcn_mfma_f32_16x16x32_bf16(qf[mt][1], kf[kb][1], s[mt][kb], 0, 0, 0);
      }

    const bool diag = (kt >= 2 * qt);
#pragma unroll
    for (int mt = 0; mt < 2; ++mt) {
      const int qrow0 = qt * 128 + wave * 32 + mt * 16 + quad * 4;
#pragma unroll
      for (int kb = 0; kb < 4; ++kb) {
        const int kcol = kt * 64 + kb * 16 + ln;
#pragma unroll
        for (int r = 0; r < 4; ++r) {
          float p = __expf(s[mt][kb][r]);
          if (diag && kcol > qrow0 + r) p = 0.f;
          l_r[mt][r] += p;
          Ps[wave][(mt * 16 + quad * 4 + r) * LDK + kb * 16 + ln] = f2bf(p);
        }
      }
    }
    __builtin_amdgcn_wave_barrier();

    bf16x8 pf[2][2];
#pragma unroll
    for (int mt = 0; mt < 2; ++mt)
#pragma unroll
      for (int kc = 0; kc < 2; ++kc)
        pf[mt][kc] = *(const bf16x8*)&Ps[wave][(mt * 16 + ln) * LDK + kc * 32 + quad * 8];
#pragma unroll
    for (int db = 0; db < 4; ++db) {
      bf16x8 vf0 = *(const bf16x8*)&Vt[(db * 16 + ln) * LDK + quad * 8];
      bf16x8 vf1 = *(const bf16x8*)&Vt[(db * 16 + ln) * LDK + 32 + quad * 8];
#pragma unroll
      for (int mt = 0; mt < 2; ++mt) {
        o_acc[mt][db] = __builtin_amdgcn_mfma_f32_16x16x32_bf16(pf[mt][0], vf0, o_acc[mt][db], 0, 0, 0);
        o_acc[mt][db] = __builtin_amdgcn_mfma_f32_16x16x32_bf16(pf[mt][1], vf1, o_acc[mt][db], 0, 0, 0);
      }
    }
  }

  const size_t obase = (size_t)b * 1024 * 512 + h * 64;
#pragma unroll
  for (int mt = 0; mt < 2; ++mt) {
    const int qrow0 = qt * 128 + wave * 32 + mt * 16 + quad * 4;
#pragma unroll
    for (int r = 0; r < 4; ++r) {
      float l = l_r[mt][r];
      l += __shfl_xor(l, 1);
      l += __shfl_xor(l, 2);
      l += __shfl_xor(l, 4);
      l += __shfl_xor(l, 8);
      const float inv = 1.f / l;
      ushort* dst = O + obase + (size_t)(qrow0 + r) * 512;
#pragma unroll
      for (int db = 0; db < 4; ++db)
        dst[db * 16 + ln] = f2bf(o_acc[mt][db][r] * inv);
    }
  }
}

// ---------------------------------------------------------------------------
// Cross-attention over 11 slots, d-parallel: one 8-lane group per q-row.
// Q l2norm x0.125 => bounded, no max. grid (32 tiles of 32 rows, 64 b*h),
// block 256 = 32 rows. Accumulates head-mean/L weights (x1/32) into mask_out.
// ---------------------------------------------------------------------------
__launch_bounds__(256)
__global__ void attn_cross(const ushort* __restrict__ Q, const ushort* __restrict__ KV,
                           ushort* __restrict__ Obf, float* __restrict__ mask_out) {
  const int rt = blockIdx.x;
  const int bh = blockIdx.y;
  const int b = bh >> 3, h = bh & 7;
  const int tid = threadIdx.x;
  __shared__ float Kcs[11][64];
  __shared__ float Vcs[11][64];
  const size_t base = ((size_t)(b * 1024)) * 512 + h * 64;

  for (int i = tid; i < 704; i += 256) {
    const int k = i >> 6, d = i & 63;
    Kcs[k][d] = bf2f(KV[((size_t)(b * 11 + k)) * 1024 + h * 64 + d]);
    Vcs[k][d] = bf2f(KV[((size_t)(b * 11 + k)) * 1024 + 512 + h * 64 + d]);
  }
  __syncthreads();

  const int g = tid >> 3;        // row group 0..31
  const int lj = tid & 7;        // lane-in-group: owns dims lj*8..lj*8+7
  const int qrow = rt * 32 + g;
  const int d0 = lj * 8;

  uint4 qv4 = *(const uint4*)(Q + base + (size_t)qrow * 512 + d0);
  const ushort* qu = (const ushort*)&qv4;
  float qv[8];
#pragma unroll
  for (int jj = 0; jj < 8; ++jj) qv[jj] = bf2f(qu[jj]);

  float s[11];
#pragma unroll
  for (int k = 0; k < 11; ++k) {
    float acc = 0.f;
#pragma unroll
    for (int jj = 0; jj < 8; ++jj) acc += qv[jj] * Kcs[k][d0 + jj];
    acc += __shfl_xor(acc, 1);
    acc += __shfl_xor(acc, 2);
    acc += __shfl_xor(acc, 4);
    s[k] = acc;
  }
  float l = 0.f;
#pragma unroll
  for (int k = 0; k < 11; ++k) { s[k] = __expf(s[k]); l += s[k]; }
  const float inv = 1.f / l;
#pragma unroll
  for (int k = 0; k < 11; ++k) s[k] *= inv;

  float* mo = mask_out + ((size_t)(b * 1024 + qrow)) * 11;
  atomicAdd(mo + lj, s[lj] * 0.03125f);
  if (lj < 3) atomicAdd(mo + lj + 8, s[lj + 8] * 0.03125f);

  ushort o8[8];
#pragma unroll
  for (int jj = 0; jj < 8; ++jj) {
    float acc = 0.f;
#pragma unroll
    for (int k = 0; k < 11; ++k) acc += s[k] * Vcs[k][d0 + jj];
    o8[jj] = f2bf(acc);
  }
  *(uint4*)(Obf + base + (size_t)qrow * 512 + d0) = *(const uint4*)o8;
}

// ---------------------------------------------------------------------------
// Host
// ---------------------------------------------------------------------------
extern "C" void kernel_launch(void* const* d_in, const int* in_sizes, int n_in,
                              void* d_out, int out_size, void* d_ws, size_t ws_size,
                              hipStream_t stream) {
  const float* features = (const float*)d_in[0];
  const float* slots    = (const float*)d_in[1];
  const float* tok_w    = (const float*)d_in[2];
  const float* tok_b    = (const float*)d_in[3];
  const float* slot_g   = (const float*)d_in[4];
  const float* slot_b   = (const float*)d_in[5];
  const float* ln1_g    = (const float*)d_in[6];
  const float* ln1_b    = (const float*)d_in[7];
  const float* ln2_g    = (const float*)d_in[8];
  const float* ln2_b    = (const float*)d_in[9];
  const float* ln3_g    = (const float*)d_in[10];
  const float* ln3_b    = (const float*)d_in[11];
  const float* sa_qw = (const float*)d_in[12]; const float* sa_qb = (const float*)d_in[13];
  const float* sa_kw = (const float*)d_in[14]; const float* sa_kb = (const float*)d_in[15];
  const float* sa_vw = (const float*)d_in[16]; const float* sa_vb = (const float*)d_in[17];
  const float* sa_ow = (const float*)d_in[18]; const float* sa_ob = (const float*)d_in[19];
  const float* ca_qw = (const float*)d_in[20]; const float* ca_qb = (const float*)d_in[21];
  const float* ca_kw = (const float*)d_in[22]; const float* ca_kb = (const float*)d_in[23];
  const float* ca_vw = (const float*)d_in[24]; const float* ca_vb = (const float*)d_in[25];
  const float* ca_ow = (const float*)d_in[26]; const float* ca_ob = (const float*)d_in[27];
  const float* ffn_w1 = (const float*)d_in[28]; const float* ffn_b1 = (const float*)d_in[29];
  const float* ffn_w2 = (const float*)d_in[30]; const float* ffn_b2 = (const float*)d_in[31];

  float* tokens = (float*)d_out;
  float* masks  = (float*)d_out + 4194304;  // 8*1024*11

  char* wp = (char*)d_ws;
  size_t off = 0;
  auto carve = [&](size_t bytes) -> void* {
    void* p = wp + off;
    off = (off + bytes + 255) & ~(size_t)255;
    return p;
  };
  ushort* hbf     = (ushort*)carve(8192ull * 512 * 2);
  ushort* qkvbf   = (ushort*)carve(8192ull * 1536 * 2);
  ushort* qbf     = (ushort*)carve(8192ull * 512 * 2);
  ushort* cbf     = (ushort*)carve(8192ull * 512 * 2);
  ushort* hidbf   = (ushort*)carve(8192ull * 2048 * 2);  // also features-bf16 alias
  ushort* slotsn  = (ushort*)carve(128ull * 512 * 2);    // rows 88..127 pad (poison ok)
  ushort* kvc     = (ushort*)carve(128ull * 1024 * 2);
  ushort* tokwbf  = (ushort*)carve(512ull * 768 * 2);
  ushort* saowbf  = (ushort*)carve(4ull * 512 * 512 * 2);
  ushort* caqwbf  = (ushort*)carve(4ull * 512 * 512 * 2);
  ushort* caowbf  = (ushort*)carve(4ull * 512 * 512 * 2);
  ushort* w1bf    = (ushort*)carve(4ull * 2048 * 512 * 2);
  ushort* w2bf    = (ushort*)carve(4ull * 512 * 2048 * 2);
  ushort* qkvwbf  = (ushort*)carve(4ull * 1536 * 512 * 2);
  ushort* kvwbf   = (ushort*)carve(4ull * 1024 * 512 * 2);
  float*  qkvb    = (float*)carve(4ull * 1536 * 4);
  float*  kvb     = (float*)carve(4ull * 1024 * 4);
  ushort* featbf  = hidbf;  // consumed by embed before ffn hidden is produced

  prep_all<<<23010, 256, 0, stream>>>(features, tok_w, sa_qw, sa_kw, sa_vw, sa_ow,
                                      ca_qw, ca_kw, ca_vw, ca_ow, ffn_w1, ffn_w2,
                                      sa_qb, sa_kb, sa_vb, ca_kb, ca_vb,
                                      featbf, tokwbf, saowbf, caqwbf, caowbf,
                                      w1bf, w2bf, qkvwbf, kvwbf, qkvb, kvb, masks);

  // token embedding: tokens = features @ tok_w^T + tok_b  (grid: m-tiles fastest)
  gemm_bt64<0><<<dim3(128, 8), 256, 0, stream>>>(featbf, tokwbf, tok_b, tokens, (ushort*)nullptr, 8192, 512, 768);
  // slots_n = LN(slots), bf16
  ln512<1><<<22, 256, 0, stream>>>(slots, slot_g, slot_b, slotsn, 88);

  for (int l = 0; l < 4; ++l) {
    const size_t wD = (size_t)l * 512 * 512;
    const size_t bD = (size_t)l * 512;
    // ---- self attention ----
    ln512<1><<<2048, 256, 0, stream>>>(tokens, ln1_g + bD, ln1_b + bD, hbf, 8192);
    gemm_bt<6><<<dim3(64, 12), 256, 0, stream>>>(hbf, qkvwbf + (size_t)l * 1536 * 512, qkvb + l * 1536,
                                                 (float*)nullptr, qkvbf, 8192, 1536, 512);
    attn_self_mfma<<<512, 256, 0, stream>>>(qkvbf, cbf);
    gemm_bt64<1><<<dim3(128, 8), 256, 0, stream>>>(cbf, saowbf + wD, sa_ob + bD, tokens, (ushort*)nullptr, 8192, 512, 512);
    // ---- cross attention ----
    ln512<1><<<2048, 256, 0, stream>>>(tokens, ln2_g + bD, ln2_b + bD, hbf, 8192);
    gemm_bt64<4><<<dim3(128, 8), 256, 0, stream>>>(hbf, caqwbf + wD, ca_qb + bD, (float*)nullptr, qbf, 8192, 512, 512);
    gemm_bt<5><<<dim3(1, 8), 256, 0, stream>>>(slotsn, kvwbf + (size_t)l * 1024 * 512, kvb + l * 1024,
                                               (float*)nullptr, kvc, 128, 1024, 512);
    attn_cross<<<dim3(32, 64), 256, 0, stream>>>(qbf, kvc, cbf, masks);
    gemm_bt64<1><<<dim3(128, 8), 256, 0, stream>>>(cbf, caowbf + wD, ca_ob + bD, tokens, (ushort*)nullptr, 8192, 512, 512);
    // ---- FFN ----
    const size_t wM = (size_t)l * 2048 * 512;
    const size_t bM = (size_t)l * 2048;
    ln512<1><<<2048, 256, 0, stream>>>(tokens, ln3_g + bD, ln3_b + bD, hbf, 8192);
    gemm_bt<2><<<dim3(64, 16), 256, 0, stream>>>(hbf, w1bf + wM, ffn_b1 + bM, (float*)nullptr, hidbf, 8192, 2048, 512);
    gemm_bt64<1><<<dim3(128, 8), 256, 0, stream>>>(hidbf, w2bf + wM, ffn_b2 + bD, tokens, (ushort*)nullptr, 8192, 512, 2048);
  }
}

// Round 11
// 973.381 us; speedup vs baseline: 1.1154x; 1.1154x over previous
//
#include <hip/hip_runtime.h>
#include <math.h>

#define DEV __device__ __forceinline__

typedef __attribute__((ext_vector_type(4))) float f32x4;
typedef __attribute__((ext_vector_type(8))) short bf16x8;

DEV ushort f2bf(float x) {
  unsigned u = __float_as_uint(x);
  u = (u + 0x7FFFu + ((u >> 16) & 1u)) >> 16;
  return (ushort)u;
}

DEV float bf2f(ushort u) { return __uint_as_float(((unsigned)u) << 16); }

DEV ushort4 cvt4(float4 f) {
  ushort4 u;
  u.x = f2bf(f.x); u.y = f2bf(f.y); u.z = f2bf(f.z); u.w = f2bf(f.w);
  return u;
}

DEV float gelu_exact(float x) {
  return 0.5f * x * (1.0f + erff(x * 0.70710678118654752f));
}

DEV void async16(const void* g, void* l) {
  __builtin_amdgcn_global_load_lds((const __attribute__((address_space(1))) void*)g,
                                   (__attribute__((address_space(3))) void*)l, 16, 0, 0);
}

// ---------------------------------------------------------------------------
// One-shot preamble: f32->bf16 weight conversions + qkv/kv packing + masks=0.
// ---------------------------------------------------------------------------
__global__ void prep_all(const float* __restrict__ features, const float* __restrict__ tok_w,
                         const float* __restrict__ sa_qw, const float* __restrict__ sa_kw,
                         const float* __restrict__ sa_vw, const float* __restrict__ sa_ow,
                         const float* __restrict__ ca_qw, const float* __restrict__ ca_kw,
                         const float* __restrict__ ca_vw, const float* __restrict__ ca_ow,
                         const float* __restrict__ ffn_w1, const float* __restrict__ ffn_w2,
                         const float* __restrict__ sa_qb, const float* __restrict__ sa_kb,
                         const float* __restrict__ sa_vb, const float* __restrict__ ca_kb,
                         const float* __restrict__ ca_vb,
                         ushort* __restrict__ featbf, ushort* __restrict__ tokwbf,
                         ushort* __restrict__ saowbf, ushort* __restrict__ caqwbf,
                         ushort* __restrict__ caowbf, ushort* __restrict__ w1bf,
                         ushort* __restrict__ w2bf, ushort* __restrict__ qkvwbf,
                         ushort* __restrict__ kvwbf, float* __restrict__ qkvb,
                         float* __restrict__ kvb, float* __restrict__ masks) {
  long i = (long)blockIdx.x * 256 + threadIdx.x;
  if (i < 1572864) { ((ushort4*)featbf)[i] = cvt4(((const float4*)features)[i]); return; }
  i -= 1572864;
  if (i < 98304) { ((ushort4*)tokwbf)[i] = cvt4(((const float4*)tok_w)[i]); return; }
  i -= 98304;
  if (i < 262144) { ((ushort4*)saowbf)[i] = cvt4(((const float4*)sa_ow)[i]); return; }
  i -= 262144;
  if (i < 262144) { ((ushort4*)caqwbf)[i] = cvt4(((const float4*)ca_qw)[i]); return; }
  i -= 262144;
  if (i < 262144) { ((ushort4*)caowbf)[i] = cvt4(((const float4*)ca_ow)[i]); return; }
  i -= 262144;
  if (i < 1048576) { ((ushort4*)w1bf)[i] = cvt4(((const float4*)ffn_w1)[i]); return; }
  i -= 1048576;
  if (i < 1048576) { ((ushort4*)w2bf)[i] = cvt4(((const float4*)ffn_w2)[i]); return; }
  i -= 1048576;
  if (i < 786432) {  // qkv weight pack: [L][3*512][512]
    const long o = i * 4;
    const int layer = (int)(o / 786432), r = (int)(o % 786432);
    const int sel = r / 262144, off = r % 262144;
    const float* s = (sel == 0 ? sa_qw : sel == 1 ? sa_kw : sa_vw) + (size_t)layer * 262144 + off;
    ((ushort4*)qkvwbf)[i] = cvt4(*(const float4*)s);
    return;
  }
  i -= 786432;
  if (i < 524288) {  // kv weight pack: [L][2*512][512] == [4096][512]
    const long o = i * 4;
    const int layer = (int)(o / 524288), r = (int)(o % 524288);
    const int sel = r / 262144, off = r % 262144;
    const float* s = (sel == 0 ? ca_kw : ca_vw) + (size_t)layer * 262144 + off;
    ((ushort4*)kvwbf)[i] = cvt4(*(const float4*)s);
    return;
  }
  i -= 524288;
  if (i < 1536) {
    const long o = i * 4;
    const int layer = (int)(o / 1536), r = (int)(o % 1536);
    const int sel = r / 512, off = r % 512;
    const float* s = (sel == 0 ? sa_qb : sel == 1 ? sa_kb : sa_vb) + layer * 512 + off;
    ((float4*)qkvb)[i] = *(const float4*)s;
    return;
  }
  i -= 1536;
  if (i < 1024) {
    const long o = i * 4;
    const int layer = (int)(o / 1024), r = (int)(o % 1024);
    const int sel = r / 512, off = r % 512;
    const float* s = (sel == 0 ? ca_kb : ca_vb) + layer * 512 + off;
    ((float4*)kvb)[i] = *(const float4*)s;
    return;
  }
  i -= 1024;
  if (i < 22528) {  // masks zero-init (8*1024*11 floats = 22528 float4)
    ((float4*)masks)[i] = make_float4(0.f, 0.f, 0.f, 0.f);
  }
}

// ---------------------------------------------------------------------------
// 128x128-tile bf16 GEMM:  Y[M,N] = A[M,K] @ W[N,K]^T + bias
// XCD-locality: m-tile = blockIdx.x (fastest varying).
// EPI 2: Ybf=bf16(gelu)  5: l2norm on even 512-chunks, plain odd (k|v packed)
// EPI 6: l2norm cols<1024, q-chunk (cols<512) additionally x0.125 (qkv)
// ---------------------------------------------------------------------------
template <int EPI>
__launch_bounds__(256, 2)
__global__ void gemm_bt(const ushort* __restrict__ A, const ushort* __restrict__ W,
                        const float* __restrict__ bias, float* __restrict__ Yf,
                        ushort* __restrict__ Ybf, int M, int N, int K) {
  __shared__ ushort As[128 * 32];
  __shared__ ushort Bs[128 * 32];
  const int tid  = threadIdx.x;
  const int lane = tid & 63;
  const int wave = tid >> 6;
  const int wr = wave >> 1, wc = wave & 1;
  const int m0 = blockIdx.x * 128, n0 = blockIdx.y * 128;   // m fastest-varying
  const int q = lane >> 4, ln = lane & 15;
  const int srow = lane >> 2;
  const int scol = (lane & 3) * 8;

  f32x4 acc[4][4] = {};

  const ushort* gA = A + (size_t)(m0 + wave * 32 + srow) * K + scol;
  const ushort* gB = W + (size_t)(n0 + wave * 32 + srow) * K + scol;
  ushort* lA = &As[(wave * 32) * 32];
  ushort* lB = &Bs[(wave * 32) * 32];

  for (int k0 = 0; k0 < K; k0 += 32) {
    async16(gA + k0, lA);
    async16(gA + k0 + (size_t)16 * K, lA + 16 * 32);
    async16(gB + k0, lB);
    async16(gB + k0 + (size_t)16 * K, lB + 16 * 32);
    __syncthreads();
    bf16x8 af[4], bfr[4];
#pragma unroll
    for (int t = 0; t < 4; ++t)
      af[t] = *(const bf16x8*)&As[(wr * 64 + t * 16 + ln) * 32 + q * 8];
#pragma unroll
    for (int t = 0; t < 4; ++t)
      bfr[t] = *(const bf16x8*)&Bs[(wc * 64 + t * 16 + ln) * 32 + q * 8];
#pragma unroll
    for (int mt = 0; mt < 4; ++mt)
#pragma unroll
      for (int nt = 0; nt < 4; ++nt)
        acc[mt][nt] = __builtin_amdgcn_mfma_f32_16x16x32_bf16(af[mt], bfr[nt], acc[mt][nt], 0, 0, 0);
    __syncthreads();
  }

  if (EPI >= 4) {
    const int chunk = (n0 + wc * 64) >> 9;
    const bool donorm = (EPI == 5 && (chunk & 1) == 0) || (EPI == 6 && chunk < 2);
    const bool doscale = (EPI == 6 && chunk == 0);
#pragma unroll
    for (int mt = 0; mt < 4; ++mt) {
      const int gm = m0 + wr * 64 + mt * 16 + q * 4;
      float val[4][4];  // [nt][r]
#pragma unroll
      for (int nt = 0; nt < 4; ++nt) {
        const float bi = bias[n0 + wc * 64 + nt * 16 + ln];
#pragma unroll
        for (int r = 0; r < 4; ++r) val[nt][r] = acc[mt][nt][r] + bi;
      }
#pragma unroll
      for (int r = 0; r < 4; ++r) {
        float mult = 1.f;
        if (donorm) {
          float ss = val[0][r]*val[0][r] + val[1][r]*val[1][r] +
                     val[2][r]*val[2][r] + val[3][r]*val[3][r];
          ss += __shfl_xor(ss, 1);
          ss += __shfl_xor(ss, 2);
          ss += __shfl_xor(ss, 4);
          ss += __shfl_xor(ss, 8);
          mult = 1.f / fmaxf(sqrtf(ss), 1e-6f);
          if (doscale) mult *= 0.125f;
        }
#pragma unroll
        for (int nt = 0; nt < 4; ++nt) {
          const int gn = n0 + wc * 64 + nt * 16 + ln;
          Ybf[(size_t)(gm + r) * N + gn] = f2bf(val[nt][r] * mult);
        }
      }
    }
  } else {
#pragma unroll
    for (int mt = 0; mt < 4; ++mt) {
      const int gm = m0 + wr * 64 + mt * 16 + q * 4;
#pragma unroll
      for (int nt = 0; nt < 4; ++nt) {
        const int gn = n0 + wc * 64 + nt * 16 + ln;
        const float bi = bias[gn];
#pragma unroll
        for (int r = 0; r < 4; ++r) {
          const float val = acc[mt][nt][r] + bi;
          const size_t idx = (size_t)(gm + r) * N + gn;
          if (EPI == 0)      Yf[idx] = val;
          else if (EPI == 1) Yf[idx] += val;
          else               Ybf[idx] = f2bf(gelu_exact(val));
        }
      }
    }
  }
}

// ---------------------------------------------------------------------------
// 64x64-tile bf16 GEMM (4 blocks/CU, R7-proven for N=512 shapes).
// XCD-locality: m-tile = blockIdx.x.
// EPI 0: Yf=val  1: Yf+=val  4: per-head l2norm x0.125 bf16 (cross-wave LDS red)
// ---------------------------------------------------------------------------
template <int EPI>
__launch_bounds__(256, 4)
__global__ void gemm_bt64(const ushort* __restrict__ A, const ushort* __restrict__ W,
                          const float* __restrict__ bias, float* __restrict__ Yf,
                          ushort* __restrict__ Ybf, int M, int N, int K) {
  __shared__ ushort As[64 * 32];
  __shared__ ushort Bs[64 * 32];
  __shared__ float red[2][32][2];
  const int tid = threadIdx.x, lane = tid & 63, wave = tid >> 6;
  const int wr = wave >> 1, wc = wave & 1;
  const int m0 = blockIdx.x * 64, n0 = blockIdx.y * 64;   // m fastest-varying
  const int q = lane >> 4, ln = lane & 15;

  f32x4 acc[2][2] = {};
  const ushort* gA = A + (size_t)(m0 + wave * 16 + (lane >> 2)) * K + (lane & 3) * 8;
  const ushort* gB = W + (size_t)(n0 + wave * 16 + (lane >> 2)) * K + (lane & 3) * 8;
  ushort* lA = &As[wave * 16 * 32];
  ushort* lB = &Bs[wave * 16 * 32];

  for (int k0 = 0; k0 < K; k0 += 32) {
    async16(gA + k0, lA);
    async16(gB + k0, lB);
    __syncthreads();
    bf16x8 af[2], bfr[2];
#pragma unroll
    for (int t = 0; t < 2; ++t)
      af[t] = *(const bf16x8*)&As[(wr * 32 + t * 16 + ln) * 32 + q * 8];
#pragma unroll
    for (int t = 0; t < 2; ++t)
      bfr[t] = *(const bf16x8*)&Bs[(wc * 32 + t * 16 + ln) * 32 + q * 8];
#pragma unroll
    for (int mt = 0; mt < 2; ++mt)
#pragma unroll
      for (int nt = 0; nt < 2; ++nt)
        acc[mt][nt] = __builtin_amdgcn_mfma_f32_16x16x32_bf16(af[mt], bfr[nt], acc[mt][nt], 0, 0, 0);
    __syncthreads();
  }

  if (EPI == 4) {
    float val[2][2][4];  // [mt][nt][r]
#pragma unroll
    for (int mt = 0; mt < 2; ++mt)
#pragma unroll
      for (int nt = 0; nt < 2; ++nt) {
        const float bi = bias[n0 + wc * 32 + nt * 16 + ln];
#pragma unroll
        for (int r = 0; r < 4; ++r) val[mt][nt][r] = acc[mt][nt][r] + bi;
      }
#pragma unroll
    for (int mt = 0; mt < 2; ++mt)
#pragma unroll
      for (int r = 0; r < 4; ++r) {
        float ss = val[mt][0][r]*val[mt][0][r] + val[mt][1][r]*val[mt][1][r];
        ss += __shfl_xor(ss, 1);
        ss += __shfl_xor(ss, 2);
        ss += __shfl_xor(ss, 4);
        ss += __shfl_xor(ss, 8);
        if (ln == 0) red[wr][mt * 16 + q * 4 + r][wc] = ss;
      }
    __syncthreads();
#pragma unroll
    for (int mt = 0; mt < 2; ++mt) {
      const int gm = m0 + wr * 32 + mt * 16 + q * 4;
#pragma unroll
      for (int r = 0; r < 4; ++r) {
        const float tot = red[wr][mt * 16 + q * 4 + r][0] + red[wr][mt * 16 + q * 4 + r][1];
        const float inv = 0.125f / fmaxf(sqrtf(tot), 1e-6f);
#pragma unroll
        for (int nt = 0; nt < 2; ++nt) {
          const int gn = n0 + wc * 32 + nt * 16 + ln;
          Ybf[(size_t)(gm + r) * N + gn] = f2bf(val[mt][nt][r] * inv);
        }
      }
    }
  } else {
#pragma unroll
    for (int mt = 0; mt < 2; ++mt) {
      const int gm = m0 + wr * 32 + mt * 16 + q * 4;
#pragma unroll
      for (int nt = 0; nt < 2; ++nt) {
        const int gn = n0 + wc * 32 + nt * 16 + ln;
        const float bi = bias[gn];
#pragma unroll
        for (int r = 0; r < 4; ++r) {
          const float val = acc[mt][nt][r] + bi;
          const size_t idx = (size_t)(gm + r) * N + gn;
          if (EPI == 0) Yf[idx] = val;
          else          Yf[idx] += val;
        }
      }
    }
  }
}

// ---------------------------------------------------------------------------
// LayerNorm over D=512, one wave per row. BF=1: bf16 out, BF=0: f32 out
// ---------------------------------------------------------------------------
template <int BF>
__launch_bounds__(256)
__global__ void ln512(const float* __restrict__ X, const float* __restrict__ G,
                      const float* __restrict__ Bb, void* __restrict__ Yv, int rows) {
  const int lane = threadIdx.x & 63;
  const int wave = threadIdx.x >> 6;
  const int row = blockIdx.x * 4 + wave;
  if (row >= rows) return;
  const float* x = X + (size_t)row * 512 + lane * 8;
  float4 v0 = *(const float4*)x;
  float4 v1 = *(const float4*)(x + 4);
  float s = v0.x + v0.y + v0.z + v0.w + v1.x + v1.y + v1.z + v1.w;
#pragma unroll
  for (int off = 32; off; off >>= 1) s += __shfl_xor(s, off);
  const float mean = s * (1.f / 512.f);
  float d[8] = {v0.x - mean, v0.y - mean, v0.z - mean, v0.w - mean,
                v1.x - mean, v1.y - mean, v1.z - mean, v1.w - mean};
  float ss = d[0]*d[0] + d[1]*d[1] + d[2]*d[2] + d[3]*d[3] +
             d[4]*d[4] + d[5]*d[5] + d[6]*d[6] + d[7]*d[7];
#pragma unroll
  for (int off = 32; off; off >>= 1) ss += __shfl_xor(ss, off);
  const float rstd = rsqrtf(ss * (1.f / 512.f) + 1e-5f);
  const float* gp = G + lane * 8;
  const float* bp = Bb + lane * 8;
  float4 g0 = *(const float4*)gp, g1 = *(const float4*)(gp + 4);
  float4 b0 = *(const float4*)bp, b1 = *(const float4*)(bp + 4);
  float y[8];
  y[0] = d[0]*rstd*g0.x + b0.x; y[1] = d[1]*rstd*g0.y + b0.y;
  y[2] = d[2]*rstd*g0.z + b0.z; y[3] = d[3]*rstd*g0.w + b0.w;
  y[4] = d[4]*rstd*g1.x + b1.x; y[5] = d[5]*rstd*g1.y + b1.y;
  y[6] = d[6]*rstd*g1.z + b1.z; y[7] = d[7]*rstd*g1.w + b1.w;
  if (BF) {
    ushort* o = (ushort*)Yv + (size_t)row * 512 + lane * 8;
    ushort4 u0, u1;
    u0.x = f2bf(y[0]); u0.y = f2bf(y[1]); u0.z = f2bf(y[2]); u0.w = f2bf(y[3]);
    u1.x = f2bf(y[4]); u1.y = f2bf(y[5]); u1.z = f2bf(y[6]); u1.w = f2bf(y[7]);
    *(ushort4*)o = u0; *(ushort4*)(o + 4) = u1;
  } else {
    float* o = (float*)Yv + (size_t)row * 512 + lane * 8;
    *(float4*)o = make_float4(y[0], y[1], y[2], y[3]);
    *(float4*)(o + 4) = make_float4(y[4], y[5], y[6], y[7]);
  }
}

// ---------------------------------------------------------------------------
// Causal self-attention, MFMA flash-style, 128-row Q tiles, pipelined staging.
// Q/K l2-normalized and Q x0.125 => |s| <= ~0.127 => NO online max needed.
// ---------------------------------------------------------------------------
__launch_bounds__(256, 2)
__global__ void attn_self_mfma(const ushort* __restrict__ QKV, ushort* __restrict__ O) {
  constexpr int LDK = 72;
  __shared__ ushort Ks[64 * LDK];
  __shared__ ushort Vt[64 * LDK];          // transposed: [d][k]
  __shared__ ushort Ps[4][32 * LDK];       // per-wave P scratch; doubles as Q staging
  ushort* Qstage = &Ps[0][0];              // [128][LDK]
  const int bi = blockIdx.x;
  const int half = bi >> 8, j = bi & 255;
  const int qt = half ? 7 - (j >> 5) : (j >> 5);
  const int bh = (half << 5) | (j & 31);
  const int b = bh >> 3, h = bh & 7;
  const size_t base = (size_t)b * 1024 * 1536 + h * 64;
  const int tid = threadIdx.x, lane = tid & 63, wave = tid >> 6;
  const int quad = lane >> 4, ln = lane & 15;

  const int kr = tid >> 2, kc0 = (tid & 3) * 16;
  const ushort* kbase = QKV + base + 512 + (size_t)kr * 1536 + kc0;
  const int vk = (tid & 31) * 2, vd0 = (tid >> 5) * 8;
  const ushort* vbase = QKV + base + 1024 + (size_t)vk * 1536 + vd0;

#pragma unroll
  for (int it = 0; it < 4; ++it) {
    const int idx = tid + 256 * it;
    const int r = idx >> 3, c = (idx & 7) * 8;
    *(uint4*)&Qstage[r * LDK + c] =
        *(const uint4*)(QKV + base + (size_t)(qt * 128 + r) * 1536 + c);
  }
  uint4 kreg0 = *(const uint4*)kbase;
  uint4 kreg1 = *(const uint4*)(kbase + 8);
  uint4 vreg0 = *(const uint4*)vbase;
  uint4 vreg1 = *(const uint4*)(vbase + 1536);
  __syncthreads();
  bf16x8 qf[2][2];
#pragma unroll
  for (int mt = 0; mt < 2; ++mt)
#pragma unroll
    for (int kc = 0; kc < 2; ++kc)
      qf[mt][kc] = *(const bf16x8*)&Qstage[(wave * 32 + mt * 16 + ln) * LDK + kc * 32 + quad * 8];

  float l_r[2][4] = {};
  f32x4 o_acc[2][4] = {};

  const int ktmax = 2 * qt + 1;
  for (int kt = 0; kt <= ktmax; ++kt) {
    __syncthreads();
    *(uint4*)&Ks[kr * LDK + kc0]     = kreg0;
    *(uint4*)&Ks[kr * LDK + kc0 + 8] = kreg1;
    {
      const ushort* ua = (const ushort*)&vreg0;
      const ushort* ub = (const ushort*)&vreg1;
#pragma unroll
      for (int jj = 0; jj < 8; ++jj)
        *(unsigned*)&Vt[(vd0 + jj) * LDK + vk] = (unsigned)ua[jj] | ((unsigned)ub[jj] << 16);
    }
    __syncthreads();
    if (kt < ktmax) {
      const size_t nb = (size_t)(kt + 1) * 64 * 1536;
      kreg0 = *(const uint4*)(kbase + nb);
      kreg1 = *(const uint4*)(kbase + nb + 8);
      vreg0 = *(const uint4*)(vbase + nb);
      vreg1 = *(const uint4*)(vbase + nb + 1536);
    }

    bf16x8 kf[4][2];
#pragma unroll
    for (int kb = 0; kb < 4; ++kb)
#pragma unroll
      for (int kc = 0; kc < 2; ++kc)
        kf[kb][kc] = *(const bf16x8*)&Ks[(kb * 16 + ln) * LDK + kc * 32 + quad * 8];
    f32x4 s[2][4] = {};
#pragma unroll
    for (int mt = 0; mt < 2; ++mt)
#pragma unroll
      for (int kb = 0; kb < 4; ++kb) {
        s[mt][kb] = __builtin_amdgcn_mfma_f32_16x16x32_bf16(qf[mt][0], kf[kb][0], s[mt][kb], 0, 0, 0);
        s[mt][kb] = __builtin_amdgcn_mfma_f32_16x16x32_bf16(qf[mt][1], kf[kb][1], s[mt][kb], 0, 0, 0);
      }

    const bool diag = (kt >= 2 * qt);
#pragma unroll
    for (int mt = 0; mt < 2; ++mt) {
      const int qrow0 = qt * 128 + wave * 32 + mt * 16 + quad * 4;
#pragma unroll
      for (int kb = 0; kb < 4; ++kb) {
        const int kcol = kt * 64 + kb * 16 + ln;
#pragma unroll
        for (int r = 0; r < 4; ++r) {
          float p = __expf(s[mt][kb][r]);
          if (diag && kcol > qrow0 + r) p = 0.f;
          l_r[mt][r] += p;
          Ps[wave][(mt * 16 + quad * 4 + r) * LDK + kb * 16 + ln] = f2bf(p);
        }
      }
    }
    __builtin_amdgcn_wave_barrier();

    bf16x8 pf[2][2];
#pragma unroll
    for (int mt = 0; mt < 2; ++mt)
#pragma unroll
      for (int kc = 0; kc < 2; ++kc)
        pf[mt][kc] = *(const bf16x8*)&Ps[wave][(mt * 16 + ln) * LDK + kc * 32 + quad * 8];
#pragma unroll
    for (int db = 0; db < 4; ++db) {
      bf16x8 vf0 = *(const bf16x8*)&Vt[(db * 16 + ln) * LDK + quad * 8];
      bf16x8 vf1 = *(const bf16x8*)&Vt[(db * 16 + ln) * LDK + 32 + quad * 8];
#pragma unroll
      for (int mt = 0; mt < 2; ++mt) {
        o_acc[mt][db] = __builtin_amdgcn_mfma_f32_16x16x32_bf16(pf[mt][0], vf0, o_acc[mt][db], 0, 0, 0);
        o_acc[mt][db] = __builtin_amdgcn_mfma_f32_16x16x32_bf16(pf[mt][1], vf1, o_acc[mt][db], 0, 0, 0);
      }
    }
  }

  const size_t obase = (size_t)b * 1024 * 512 + h * 64;
#pragma unroll
  for (int mt = 0; mt < 2; ++mt) {
    const int qrow0 = qt * 128 + wave * 32 + mt * 16 + quad * 4;
#pragma unroll
    for (int r = 0; r < 4; ++r) {
      float l = l_r[mt][r];
      l += __shfl_xor(l, 1);
      l += __shfl_xor(l, 2);
      l += __shfl_xor(l, 4);
      l += __shfl_xor(l, 8);
      const float inv = 1.f / l;
      ushort* dst = O + obase + (size_t)(qrow0 + r) * 512;
#pragma unroll
      for (int db = 0; db < 4; ++db)
        dst[db * 16 + ln] = f2bf(o_acc[mt][db][r] * inv);
    }
  }
}

// ---------------------------------------------------------------------------
// Cross-attention over 11 slots, d-parallel: one 8-lane group per q-row.
// KV packed for ALL layers: [88 rows][4096] (layer l at col l*1024, k|v halves).
// grid (32 tiles of 32 rows, 64 b*h), block 256 = 32 rows.
// ---------------------------------------------------------------------------
__launch_bounds__(256)
__global__ void attn_cross(const ushort* __restrict__ Q, const ushort* __restrict__ KV,
                           int loff, ushort* __restrict__ Obf, float* __restrict__ mask_out) {
  const int rt = blockIdx.x;
  const int bh = blockIdx.y;
  const int b = bh >> 3, h = bh & 7;
  const int tid = threadIdx.x;
  __shared__ float Kcs[11][64];
  __shared__ float Vcs[11][64];
  const size_t base = ((size_t)(b * 1024)) * 512 + h * 64;

  for (int i = tid; i < 704; i += 256) {
    const int k = i >> 6, d = i & 63;
    Kcs[k][d] = bf2f(KV[((size_t)(b * 11 + k)) * 4096 + loff + h * 64 + d]);
    Vcs[k][d] = bf2f(KV[((size_t)(b * 11 + k)) * 4096 + loff + 512 + h * 64 + d]);
  }
  __syncthreads();

  const int g = tid >> 3;        // row group 0..31
  const int lj = tid & 7;        // lane-in-group: owns dims lj*8..lj*8+7
  const int qrow = rt * 32 + g;
  const int d0 = lj * 8;

  uint4 qv4 = *(const uint4*)(Q + base + (size_t)qrow * 512 + d0);
  const ushort* qu = (const ushort*)&qv4;
  float qv[8];
#pragma unroll
  for (int jj = 0; jj < 8; ++jj) qv[jj] = bf2f(qu[jj]);

  float s[11];
#pragma unroll
  for (int k = 0; k < 11; ++k) {
    float acc = 0.f;
#pragma unroll
    for (int jj = 0; jj < 8; ++jj) acc += qv[jj] * Kcs[k][d0 + jj];
    acc += __shfl_xor(acc, 1);
    acc += __shfl_xor(acc, 2);
    acc += __shfl_xor(acc, 4);
    s[k] = acc;
  }
  float l = 0.f;
#pragma unroll
  for (int k = 0; k < 11; ++k) { s[k] = __expf(s[k]); l += s[k]; }
  const float inv = 1.f / l;
#pragma unroll
  for (int k = 0; k < 11; ++k) s[k] *= inv;

  float* mo = mask_out + ((size_t)(b * 1024 + qrow)) * 11;
  atomicAdd(mo + lj, s[lj] * 0.03125f);
  if (lj < 3) atomicAdd(mo + lj + 8, s[lj + 8] * 0.03125f);

  ushort o8[8];
#pragma unroll
  for (int jj = 0; jj < 8; ++jj) {
    float acc = 0.f;
#pragma unroll
    for (int k = 0; k < 11; ++k) acc += s[k] * Vcs[k][d0 + jj];
    o8[jj] = f2bf(acc);
  }
  *(uint4*)(Obf + base + (size_t)qrow * 512 + d0) = *(const uint4*)o8;
}

// ---------------------------------------------------------------------------
// Host
// ---------------------------------------------------------------------------
extern "C" void kernel_launch(void* const* d_in, const int* in_sizes, int n_in,
                              void* d_out, int out_size, void* d_ws, size_t ws_size,
                              hipStream_t stream) {
  const float* features = (const float*)d_in[0];
  const float* slots    = (const float*)d_in[1];
  const float* tok_w    = (const float*)d_in[2];
  const float* tok_b    = (const float*)d_in[3];
  const float* slot_g   = (const float*)d_in[4];
  const float* slot_b   = (const float*)d_in[5];
  const float* ln1_g    = (const float*)d_in[6];
  const float* ln1_b    = (const float*)d_in[7];
  const float* ln2_g    = (const float*)d_in[8];
  const float* ln2_b    = (const float*)d_in[9];
  const float* ln3_g    = (const float*)d_in[10];
  const float* ln3_b    = (const float*)d_in[11];
  const float* sa_qw = (const float*)d_in[12]; const float* sa_qb = (const float*)d_in[13];
  const float* sa_kw = (const float*)d_in[14]; const float* sa_kb = (const float*)d_in[15];
  const float* sa_vw = (const float*)d_in[16]; const float* sa_vb = (const float*)d_in[17];
  const float* sa_ow = (const float*)d_in[18]; const float* sa_ob = (const float*)d_in[19];
  const float* ca_qw = (const float*)d_in[20]; const float* ca_qb = (const float*)d_in[21];
  const float* ca_kw = (const float*)d_in[22]; const float* ca_kb = (const float*)d_in[23];
  const float* ca_vw = (const float*)d_in[24]; const float* ca_vb = (const float*)d_in[25];
  const float* ca_ow = (const float*)d_in[26]; const float* ca_ob = (const float*)d_in[27];
  const float* ffn_w1 = (const float*)d_in[28]; const float* ffn_b1 = (const float*)d_in[29];
  const float* ffn_w2 = (const float*)d_in[30]; const float* ffn_b2 = (const float*)d_in[31];

  float* tokens = (float*)d_out;
  float* masks  = (float*)d_out + 4194304;  // 8*1024*11

  char* wp = (char*)d_ws;
  size_t off = 0;
  auto carve = [&](size_t bytes) -> void* {
    void* p = wp + off;
    off = (off + bytes + 255) & ~(size_t)255;
    return p;
  };
  ushort* hbf     = (ushort*)carve(8192ull * 512 * 2);
  ushort* qkvbf   = (ushort*)carve(8192ull * 1536 * 2);
  ushort* qbf     = (ushort*)carve(8192ull * 512 * 2);
  ushort* cbf     = (ushort*)carve(8192ull * 512 * 2);
  ushort* hidbf   = (ushort*)carve(8192ull * 2048 * 2);  // also features-bf16 alias
  ushort* slotsn  = (ushort*)carve(128ull * 512 * 2);    // rows 88..127 pad (poison ok)
  ushort* kvc     = (ushort*)carve(128ull * 4096 * 2);   // all 4 layers' k|v packed
  ushort* tokwbf  = (ushort*)carve(512ull * 768 * 2);
  ushort* saowbf  = (ushort*)carve(4ull * 512 * 512 * 2);
  ushort* caqwbf  = (ushort*)carve(4ull * 512 * 512 * 2);
  ushort* caowbf  = (ushort*)carve(4ull * 512 * 512 * 2);
  ushort* w1bf    = (ushort*)carve(4ull * 2048 * 512 * 2);
  ushort* w2bf    = (ushort*)carve(4ull * 512 * 2048 * 2);
  ushort* qkvwbf  = (ushort*)carve(4ull * 1536 * 512 * 2);
  ushort* kvwbf   = (ushort*)carve(4ull * 1024 * 512 * 2);   // == [4096][512]
  float*  qkvb    = (float*)carve(4ull * 1536 * 4);
  float*  kvb     = (float*)carve(4ull * 1024 * 4);          // == [4096]
  ushort* featbf  = hidbf;  // consumed by embed before ffn hidden is produced

  prep_all<<<23010, 256, 0, stream>>>(features, tok_w, sa_qw, sa_kw, sa_vw, sa_ow,
                                      ca_qw, ca_kw, ca_vw, ca_ow, ffn_w1, ffn_w2,
                                      sa_qb, sa_kb, sa_vb, ca_kb, ca_vb,
                                      featbf, tokwbf, saowbf, caqwbf, caowbf,
                                      w1bf, w2bf, qkvwbf, kvwbf, qkvb, kvb, masks);

  // token embedding: tokens = features @ tok_w^T + tok_b  (grid: m-tiles fastest)
  gemm_bt64<0><<<dim3(128, 8), 256, 0, stream>>>(featbf, tokwbf, tok_b, tokens, (ushort*)nullptr, 8192, 512, 768);
  // slots_n = LN(slots), bf16
  ln512<1><<<22, 256, 0, stream>>>(slots, slot_g, slot_b, slotsn, 88);
  // ALL layers' slot k|v projections in one GEMM: [128]x[4096] (k-halves l2normed)
  gemm_bt<5><<<dim3(1, 32), 256, 0, stream>>>(slotsn, kvwbf, kvb,
                                              (float*)nullptr, kvc, 128, 4096, 512);

  for (int l = 0; l < 4; ++l) {
    const size_t wD = (size_t)l * 512 * 512;
    const size_t bD = (size_t)l * 512;
    // ---- self attention ----
    ln512<1><<<2048, 256, 0, stream>>>(tokens, ln1_g + bD, ln1_b + bD, hbf, 8192);
    gemm_bt<6><<<dim3(64, 12), 256, 0, stream>>>(hbf, qkvwbf + (size_t)l * 1536 * 512, qkvb + l * 1536,
                                                 (float*)nullptr, qkvbf, 8192, 1536, 512);
    attn_self_mfma<<<512, 256, 0, stream>>>(qkvbf, cbf);
    gemm_bt64<1><<<dim3(128, 8), 256, 0, stream>>>(cbf, saowbf + wD, sa_ob + bD, tokens, (ushort*)nullptr, 8192, 512, 512);
    // ---- cross attention ----
    ln512<1><<<2048, 256, 0, stream>>>(tokens, ln2_g + bD, ln2_b + bD, hbf, 8192);
    gemm_bt64<4><<<dim3(128, 8), 256, 0, stream>>>(hbf, caqwbf + wD, ca_qb + bD, (float*)nullptr, qbf, 8192, 512, 512);
    attn_cross<<<dim3(32, 64), 256, 0, stream>>>(qbf, kvc, l * 1024, cbf, masks);
    gemm_bt64<1><<<dim3(128, 8), 256, 0, stream>>>(cbf, caowbf + wD, ca_ob + bD, tokens, (ushort*)nullptr, 8192, 512, 512);
    // ---- FFN ----
    const size_t wM = (size_t)l * 2048 * 512;
    const size_t bM = (size_t)l * 2048;
    ln512<1><<<2048, 256, 0, stream>>>(tokens, ln3_g + bD, ln3_b + bD, hbf, 8192);
    gemm_bt<2><<<dim3(64, 16), 256, 0, stream>>>(hbf, w1bf + wM, ffn_b1 + bM, (float*)nullptr, hidbf, 8192, 2048, 512);
    gemm_bt64<1><<<dim3(128, 8), 256, 0, stream>>>(hidbf, w2bf + wM, ffn_b2 + bD, tokens, (ushort*)nullptr, 8192, 512, 2048);
  }
}